// Round 1
// baseline (5225.520 us; speedup 1.0000x reference)
//
#include <hip/hip_runtime.h>
#include <hip/hip_bf16.h>

#define B_SZ 4096
#define T_SZ 365
#define IN_SZ 32
#define H_SZ 256
#define G4 1024       // 4*H
#define K_SZ 288      // H + IN (K dim of fused gate GEMM)
#define KP 296        // padded LDS row stride (bank-conflict-free: 148 dw, gcd(148,32)=4 -> 2-way only)
#define M_TILE 32     // batch rows per block
#define NBLK (B_SZ / M_TILE)   // 128
#define NTHR 512      // 8 waves

typedef __bf16 bf16x8 __attribute__((ext_vector_type(8)));
typedef float f32x4 __attribute__((ext_vector_type(4)));

__device__ __forceinline__ float fast_sigmoid(float x) {
    float e = __builtin_amdgcn_exp2f(-1.4426950408889634f * x);
    return __builtin_amdgcn_rcpf(1.0f + e);
}
__device__ __forceinline__ float fast_tanh(float x) {
    // tanh(x) = 1 - 2/(1+exp2(2*log2e*x)); saturates gracefully at +-1
    float e = __builtin_amdgcn_exp2f(2.8853900817779268f * x);
    return 1.0f - 2.0f * __builtin_amdgcn_rcpf(1.0f + e);
}

// Pack W = [w_hh | w_ih] as bf16, layout [g][k] (k contiguous) = B^T for MFMA B-frags.
__global__ void pack_w_kernel(const float* __restrict__ w_ih,
                              const float* __restrict__ w_hh,
                              __bf16* __restrict__ wp) {
    int idx = blockIdx.x * 256 + threadIdx.x;
    if (idx >= G4 * K_SZ) return;
    int g = idx / K_SZ, k = idx - g * K_SZ;
    float v = (k < H_SZ) ? w_hh[g * H_SZ + k] : w_ih[g * IN_SZ + (k - H_SZ)];
    wp[idx] = (__bf16)v;
}

__global__ __launch_bounds__(NTHR, 2) void lstm_kernel(
    const float* __restrict__ xd, const float* __restrict__ b,
    const __bf16* __restrict__ wp, const float* __restrict__ w_out,
    const float* __restrict__ b_out, float* __restrict__ out)
{
    // A-operand staging: h (cols 0..255) + x (cols 256..287), split hi/lo bf16
    __shared__ __bf16 a_hi[M_TILE * KP];
    __shared__ __bf16 a_lo[M_TILE * KP];

    const int tid  = threadIdx.x;
    const int wv   = tid >> 6;       // wave 0..7
    const int lane = tid & 63;
    const int quad = lane >> 4;      // 0..3
    const int l16  = lane & 15;      // 0..15
    const int blk  = blockIdx.x;

    // zero initial h state (x region overwritten every step; pad never read by MFMA frags)
    for (int i = tid; i < M_TILE * KP; i += NTHR) {
        a_hi[i] = (__bf16)0.f;
        a_lo[i] = (__bf16)0.f;
    }

    // Per-lane biases: gate G in {i,f,g,o}, group gi in {0,1}; col j = (wv+8*gi)*16 + l16
    float bias[4][2];
#pragma unroll
    for (int G = 0; G < 4; ++G)
#pragma unroll
        for (int gi = 0; gi < 2; ++gi)
            bias[G][gi] = b[G * H_SZ + (wv + 8 * gi) * 16 + l16];

    const f32x4 vzero = {0.f, 0.f, 0.f, 0.f};
    f32x4 creg[2][2];  // [row-tile][group], 4 rows per vector
#pragma unroll
    for (int rt = 0; rt < 2; ++rt)
#pragma unroll
        for (int gi = 0; gi < 2; ++gi) creg[rt][gi] = vzero;

    // x loader: each thread owns 2 consecutive floats of one row
    const int xm = tid >> 4;           // row 0..31
    const int xe = (tid & 15) * 2;     // element 0..30
    const float* xrow = xd + (size_t)(blk * M_TILE + xm) * (T_SZ * IN_SZ) + xe;
    float2 xv = *(const float2*)xrow;  // t = 0

    for (int t = 0; t < T_SZ; ++t) {
        // stage x_t into LDS (hi/lo split)
        {
            __bf16 h0 = (__bf16)xv.x; __bf16 l0 = (__bf16)(xv.x - (float)h0);
            __bf16 h1 = (__bf16)xv.y; __bf16 l1 = (__bf16)(xv.y - (float)h1);
            int base = xm * KP + H_SZ + xe;
            a_hi[base] = h0; a_hi[base + 1] = h1;
            a_lo[base] = l0; a_lo[base + 1] = l1;
        }
        __syncthreads();

        // ---- GEMM: gates[32 x 1024] = [a_hi + a_lo][32 x 288] @ W^T ----
        f32x4 acc[2][8];
#pragma unroll
        for (int rt = 0; rt < 2; ++rt)
#pragma unroll
            for (int c = 0; c < 8; ++c) acc[rt][c] = vzero;

#pragma unroll
        for (int kt = 0; kt < 9; ++kt) {
            const int k0 = kt * 32 + quad * 8;
            bf16x8 ah0 = *(const bf16x8*)&a_hi[l16 * KP + k0];
            bf16x8 ah1 = *(const bf16x8*)&a_hi[(16 + l16) * KP + k0];
            bf16x8 al0 = *(const bf16x8*)&a_lo[l16 * KP + k0];
            bf16x8 al1 = *(const bf16x8*)&a_lo[(16 + l16) * KP + k0];
#pragma unroll
            for (int c = 0; c < 8; ++c) {
                const int tile = wv + 8 * c;   // col-tile; wave owns t%8==wv -> all 4 gates co-located
                bf16x8 bf = *(const bf16x8*)(wp + (size_t)(tile * 16 + l16) * K_SZ + kt * 32 + quad * 8);
                acc[0][c] = __builtin_amdgcn_mfma_f32_16x16x32_bf16(ah0, bf, acc[0][c], 0, 0, 0);
                acc[0][c] = __builtin_amdgcn_mfma_f32_16x16x32_bf16(al0, bf, acc[0][c], 0, 0, 0);
                acc[1][c] = __builtin_amdgcn_mfma_f32_16x16x32_bf16(ah1, bf, acc[1][c], 0, 0, 0);
                acc[1][c] = __builtin_amdgcn_mfma_f32_16x16x32_bf16(al1, bf, acc[1][c], 0, 0, 0);
            }
        }
        __syncthreads();  // all waves done reading old h before we overwrite it

        // prefetch next x while doing activation math
        if (t + 1 < T_SZ) xv = *(const float2*)(xrow + (size_t)(t + 1) * IN_SZ);

        // ---- activations + state update (fp32) ----
        // acc[rt][c]: c = 2*G + gi; C-layout row = quad*4 + r, col = l16 (within tile)
#pragma unroll
        for (int rt = 0; rt < 2; ++rt) {
#pragma unroll
            for (int gi = 0; gi < 2; ++gi) {
                const int j = (wv + 8 * gi) * 16 + l16;  // h column
                f32x4 ip = acc[rt][0 + gi];
                f32x4 fp = acc[rt][2 + gi];
                f32x4 gp = acc[rt][4 + gi];
                f32x4 op = acc[rt][6 + gi];
#pragma unroll
                for (int r = 0; r < 4; ++r) {
                    float iv = fast_sigmoid(ip[r] + bias[0][gi]);
                    float fv = fast_sigmoid(fp[r] + bias[1][gi]);
                    float gv = fast_tanh(gp[r] + bias[2][gi]);
                    float ov = fast_sigmoid(op[r] + bias[3][gi]);
                    float cv = fv * creg[rt][gi][r] + iv * gv;
                    creg[rt][gi][r] = cv;
                    float hv = ov * fast_tanh(cv);
                    __bf16 hh = (__bf16)hv;
                    __bf16 hl = (__bf16)(hv - (float)hh);
                    const int m = rt * 16 + quad * 4 + r;
                    a_hi[m * KP + j] = hh;
                    a_lo[m * KP + j] = hl;
                }
            }
        }
    }
    __syncthreads();

    // ---- epilogue: out[m] = relu(h_T . w_out + b_out); h reconstructed as hi+lo ----
    {
        const int m = tid >> 4;
        const int p = tid & 15;
        float s = 0.f;
#pragma unroll
        for (int jj = 0; jj < 16; ++jj) {
            int j = p * 16 + jj;
            s += ((float)a_hi[m * KP + j] + (float)a_lo[m * KP + j]) * w_out[j];
        }
        s += __shfl_xor(s, 1);
        s += __shfl_xor(s, 2);
        s += __shfl_xor(s, 4);
        s += __shfl_xor(s, 8);
        if (p == 0) out[blk * M_TILE + m] = fmaxf(s + b_out[0], 0.f);
    }
}

extern "C" void kernel_launch(void* const* d_in, const int* in_sizes, int n_in,
                              void* d_out, int out_size, void* d_ws, size_t ws_size,
                              hipStream_t stream) {
    const float* xd    = (const float*)d_in[0];
    const float* w_ih  = (const float*)d_in[1];
    const float* w_hh  = (const float*)d_in[2];
    const float* b     = (const float*)d_in[3];
    const float* w_out = (const float*)d_in[4];
    const float* b_out = (const float*)d_in[5];
    float* out = (float*)d_out;

    __bf16* wp = (__bf16*)d_ws;  // 1024*288*2 = 576 KB

    int pack_elems = G4 * K_SZ;
    pack_w_kernel<<<(pack_elems + 255) / 256, 256, 0, stream>>>(w_ih, w_hh, wp);
    lstm_kernel<<<NBLK, NTHR, 0, stream>>>(xd, b, wp, w_out, b_out, out);
}